// Round 2
// baseline (545.827 us; speedup 1.0000x reference)
//
#include <hip/hip_runtime.h>
#include <hip/hip_bf16.h>
#include <stdint.h>

// Problem constants
#define BB   64
#define NN   2048
#define CONC 512
#define FUSEF 1024
#define HIDH 512

typedef short  bf16x8 __attribute__((ext_vector_type(8)));   // 8 bf16 in 4 VGPRs
typedef unsigned short u16x8 __attribute__((ext_vector_type(8)));
typedef float  f32x4  __attribute__((ext_vector_type(4)));

#define GLOBAL_U32(p) ((const __attribute__((address_space(1))) unsigned int*)(p))
#define LDS_U32(p)    ((__attribute__((address_space(3))) unsigned int*)(p))

__device__ __forceinline__ unsigned short f2bf(float f) {
    unsigned u = __builtin_bit_cast(unsigned, f);
    u += 0x7fffu + ((u >> 16) & 1u);          // RNE
    return (unsigned short)(u >> 16);
}

__device__ __forceinline__ float fast_tanh(float x) {
    // 1 - 2/(exp(2x)+1); exp->inf => 1, exp->0 => -1. ~1e-6 rel err.
    return 1.0f - 2.0f / (__expf(2.0f * x) + 1.0f);
}

// ---------------- K1a: query[b,h] = sum_f fuse[b,f] * Wq[h,f] ----------------
__global__ __launch_bounds__(512)
void query_kernel(const float* __restrict__ fuse, const float* __restrict__ wq,
                  float* __restrict__ query) {
    __shared__ float fs[FUSEF];
    const int b = blockIdx.x, tid = threadIdx.x;
    fs[tid]       = fuse[b * FUSEF + tid];
    fs[tid + 512] = fuse[b * FUSEF + tid + 512];
    __syncthreads();
    const float* w = wq + (long)tid * FUSEF;
    float a0 = 0.f, a1 = 0.f, a2 = 0.f, a3 = 0.f;
    #pragma unroll 4
    for (int f = 0; f < FUSEF; f += 4) {
        float4 wf = *(const float4*)(w + f);
        a0 += wf.x * fs[f];     a1 += wf.y * fs[f + 1];
        a2 += wf.z * fs[f + 2]; a3 += wf.w * fs[f + 3];
    }
    query[b * HIDH + tid] = (a0 + a1) + (a2 + a3);
}

// ---------------- K1b: pack Wk (f32 [512][512]) -> bf16, tiled+swizzled -----
// ws layout: 8 K-tiles of 64KB; within tile kk: byte = h*128 + ((kloc*2) ^ ((h&7)<<4))
__global__ __launch_bounds__(256)
void pack_wk(const float* __restrict__ wk, char* __restrict__ wkb) {
    const int u  = blockIdx.x * 256 + threadIdx.x;   // 0..32767 (16B units)
    const int h  = u >> 6;
    const int k0 = (u & 63) << 3;                    // 0..504 step 8
    const float* src = wk + (long)h * CONC + k0;
    float4 f0 = *(const float4*)src;
    float4 f1 = *(const float4*)(src + 4);
    u16x8 v;
    v[0] = f2bf(f0.x); v[1] = f2bf(f0.y); v[2] = f2bf(f0.z); v[3] = f2bf(f0.w);
    v[4] = f2bf(f1.x); v[5] = f2bf(f1.y); v[6] = f2bf(f1.z); v[7] = f2bf(f1.w);
    const int kk = k0 >> 6, kloc = k0 & 63;
    const int off = kk * 65536 + h * 128 + (((kloc * 2)) ^ ((h & 7) << 4));
    *(u16x8*)(wkb + off) = v;
}

// ---------------- K2: scores[bn] = sum_h tanh(q[b,h]+k[bn,h]) * Wt[h] --------
// Tile: 64 rows x 512 h (full H), K-loop BK=64 over CON=512.
// 8 waves: wr = wid>>2 (2 row groups of 32), wc = wid&3 (4 col groups of 128).
__global__ __launch_bounds__(512)
void score_kernel(const float* __restrict__ conf, const char* __restrict__ wkb,
                  const float* __restrict__ query, const float* __restrict__ wt,
                  float* __restrict__ scores) {
    __shared__ __align__(16) char As[64 * 128];    // 8 KB  (bf16, swizzled)
    __shared__ __align__(16) char Bs[512 * 128];   // 64 KB (bf16, swizzled via pre-swz ws)
    __shared__ float qs[HIDH];
    __shared__ float wts[HIDH];
    __shared__ float sp[64];

    const int tid  = threadIdx.x;
    const int lane = tid & 63;
    const int wid  = tid >> 6;
    const int wr   = wid >> 2;
    const int wc   = wid & 3;
    const long row0 = (long)blockIdx.x * 64;
    const int  b    = (int)(row0 >> 11);

    qs[tid]  = query[b * HIDH + tid];
    wts[tid] = wt[tid];
    if (tid < 64) sp[tid] = 0.f;

    f32x4 acc[2][8] = {};

    const float* aGlob = conf + row0 * CONC;
    // A-staging coords (fixed per thread)
    const int arow = tid >> 3;
    const int akc  = (tid & 7) << 3;             // k element offset (8 elems = 16B)
    const int aoff = arow * 128 + (((akc * 2)) ^ ((arow & 7) << 4));

    for (int kk = 0; kk < 8; ++kk) {
        // --- stage A: 64x64 f32 -> bf16 -> LDS (swizzled) ---
        {
            const float* src = aGlob + (long)arow * CONC + kk * 64 + akc;
            float4 f0 = *(const float4*)src;
            float4 f1 = *(const float4*)(src + 4);
            u16x8 v;
            v[0] = f2bf(f0.x); v[1] = f2bf(f0.y); v[2] = f2bf(f0.z); v[3] = f2bf(f0.w);
            v[4] = f2bf(f1.x); v[5] = f2bf(f1.y); v[6] = f2bf(f1.z); v[7] = f2bf(f1.w);
            *(u16x8*)(As + aoff) = v;
        }
        // --- stage B: 64KB pre-swizzled tile, linear copy via global_load_lds ---
        {
            const char* btile = wkb + kk * 65536;
            #pragma unroll
            for (int i = 0; i < 8; ++i) {
                const int off = wid * 8192 + i * 1024;   // wave-uniform
                __builtin_amdgcn_global_load_lds(
                    GLOBAL_U32(btile + off + (lane << 4)),
                    LDS_U32(Bs + off),
                    16, 0, 0);
            }
        }
        __syncthreads();
        // --- compute: 2 k-steps of 32 ---
        #pragma unroll
        for (int ks = 0; ks < 2; ++ks) {
            const int kb = (ks * 32 + ((lane >> 4) << 3)) * 2;   // byte within 128
            bf16x8 af[2];
            #pragma unroll
            for (int rf = 0; rf < 2; ++rf) {
                const int r = wr * 32 + rf * 16 + (lane & 15);
                af[rf] = *(const bf16x8*)(As + r * 128 + (kb ^ ((r & 7) << 4)));
            }
            bf16x8 bfr[8];
            #pragma unroll
            for (int cf = 0; cf < 8; ++cf) {
                const int h = wc * 128 + cf * 16 + (lane & 15);
                bfr[cf] = *(const bf16x8*)(Bs + h * 128 + (kb ^ ((h & 7) << 4)));
            }
            #pragma unroll
            for (int rf = 0; rf < 2; ++rf)
                #pragma unroll
                for (int cf = 0; cf < 8; ++cf)
                    acc[rf][cf] = __builtin_amdgcn_mfma_f32_16x16x32_bf16(
                        af[rf], bfr[cf], acc[rf][cf], 0, 0, 0);
        }
        __syncthreads();
    }

    // --- epilogue: tanh(q+k)*wt, reduce over h ---
    float ps[2][4] = {};
    const int cb = wc * 128 + (lane & 15);
    #pragma unroll
    for (int rf = 0; rf < 2; ++rf)
        #pragma unroll
        for (int cf = 0; cf < 8; ++cf) {
            const int col = cb + cf * 16;
            const float q = qs[col], w = wts[col];
            #pragma unroll
            for (int j = 0; j < 4; ++j)
                ps[rf][j] += fast_tanh(acc[rf][cf][j] + q) * w;
        }
    #pragma unroll
    for (int m = 1; m < 16; m <<= 1) {
        #pragma unroll
        for (int rf = 0; rf < 2; ++rf)
            #pragma unroll
            for (int j = 0; j < 4; ++j)
                ps[rf][j] += __shfl_xor(ps[rf][j], m);
    }
    if ((lane & 15) == 0) {
        const int rb = wr * 32 + ((lane >> 4) << 2);
        #pragma unroll
        for (int rf = 0; rf < 2; ++rf)
            #pragma unroll
            for (int j = 0; j < 4; ++j)
                atomicAdd(&sp[rb + rf * 16 + j], ps[rf][j]);
    }
    __syncthreads();
    if (tid < 64) scores[row0 + tid] = sp[tid];
}

// ---------------- K3: softmax over N + weighted sum -> fin[b, c] -------------
// grid: B*8 blocks; block handles (b, 64-col chunk); 256 threads.
__global__ __launch_bounds__(256)
void out_kernel(const float* __restrict__ conf, const float* __restrict__ prob,
                const float* __restrict__ scores, float* __restrict__ fin) {
    __shared__ float wl[NN];          // exp(s-max)*prob
    __shared__ float4 red[16 * 16];   // 16 n-groups x 16 col4
    __shared__ float smax[4], ssum[4];

    const int tid = threadIdx.x;
    const int b   = blockIdx.x >> 3;
    const int c0  = (blockIdx.x & 7) * 64;
    const float* sc = scores + b * NN;

    float mx = -1e30f;
    for (int n = tid; n < NN; n += 256) mx = fmaxf(mx, sc[n]);
    #pragma unroll
    for (int m = 1; m < 64; m <<= 1) mx = fmaxf(mx, __shfl_xor(mx, m));
    if ((tid & 63) == 0) smax[tid >> 6] = mx;
    __syncthreads();
    mx = fmaxf(fmaxf(smax[0], smax[1]), fmaxf(smax[2], smax[3]));

    float sm = 0.f;
    const float* pb = prob + b * NN;
    for (int n = tid; n < NN; n += 256) {
        const float e = __expf(sc[n] - mx);
        wl[n] = e * pb[n];
        sm += e;
    }
    #pragma unroll
    for (int m = 1; m < 64; m <<= 1) sm += __shfl_xor(sm, m);
    if ((tid & 63) == 0) ssum[tid >> 6] = sm;
    __syncthreads();
    const float rsum = 1.0f / (ssum[0] + ssum[1] + ssum[2] + ssum[3]);

    const int c4 = (tid & 15) << 2;   // col within chunk
    const int ng = tid >> 4;          // 16 n-groups
    const float* cb = conf + (long)b * NN * CONC + c0 + c4;
    float4 acc = make_float4(0.f, 0.f, 0.f, 0.f);
    for (int n = ng; n < NN; n += 16) {
        const float w = wl[n];
        float4 v = *(const float4*)(cb + (long)n * CONC);
        acc.x += w * v.x; acc.y += w * v.y; acc.z += w * v.z; acc.w += w * v.w;
    }
    red[ng * 16 + (tid & 15)] = acc;
    __syncthreads();
    if (tid < 16) {
        float4 s = red[tid];
        #pragma unroll
        for (int g = 1; g < 16; ++g) {
            float4 t = red[g * 16 + tid];
            s.x += t.x; s.y += t.y; s.z += t.z; s.w += t.w;
        }
        s.x *= rsum; s.y *= rsum; s.z *= rsum; s.w *= rsum;
        *(float4*)(fin + b * CONC + c0 + (tid << 2)) = s;
    }
}

extern "C" void kernel_launch(void* const* d_in, const int* in_sizes, int n_in,
                              void* d_out, int out_size, void* d_ws, size_t ws_size,
                              hipStream_t stream) {
    const float* conf = (const float*)d_in[0];
    const float* fuse = (const float*)d_in[1];
    const float* prob = (const float*)d_in[2];
    const float* wq   = (const float*)d_in[3];
    const float* wk   = (const float*)d_in[4];
    const float* wt   = (const float*)d_in[5];
    float* out = (float*)d_out;
    char* ws = (char*)d_ws;

    float* q_ws  = (float*)ws;                    // 64*512*4   = 128 KB
    float* sc_ws = (float*)(ws + 131072);         // 64*2048*4  = 512 KB
    char*  wkb   = ws + 655360;                   // 512*512*2  = 512 KB (swizzled tiles)

    query_kernel<<<dim3(BB), dim3(512), 0, stream>>>(fuse, wq, q_ws);
    pack_wk<<<dim3(128), dim3(256), 0, stream>>>(wk, wkb);
    score_kernel<<<dim3((BB * NN) / 64), dim3(512), 0, stream>>>(conf, wkb, q_ws, wt, sc_ws);
    out_kernel<<<dim3(BB * 8), dim3(256), 0, stream>>>(conf, prob, sc_ws, out);
}

// Round 4
// 512.168 us; speedup vs baseline: 1.0657x; 1.0657x over previous
//
#include <hip/hip_runtime.h>
#include <hip/hip_bf16.h>
#include <stdint.h>

// Problem constants
#define BB   64
#define NN   2048
#define CONC 512
#define FUSEF 1024
#define HIDH 512

typedef short  bf16x8 __attribute__((ext_vector_type(8)));   // 8 bf16 in 4 VGPRs
typedef unsigned short u16x8 __attribute__((ext_vector_type(8)));
typedef float  f32x4  __attribute__((ext_vector_type(4)));

#define GLOBAL_U32(p) ((const __attribute__((address_space(1))) unsigned int*)(p))
#define LDS_U32(p)    ((__attribute__((address_space(3))) unsigned int*)(p))

__device__ __forceinline__ unsigned short f2bf(float f) {
    unsigned u = __builtin_bit_cast(unsigned, f);
    u += 0x7fffu + ((u >> 16) & 1u);          // RNE
    return (unsigned short)(u >> 16);
}

__device__ __forceinline__ float fast_tanh(float x) {
    return 1.0f - 2.0f / (__expf(2.0f * x) + 1.0f);
}

// ---------------- K1a: query[b,h] = sum_f fuse[b,f] * Wq[h,f] ----------------
// grid: 64 b x 8 h-chunks of 64. 256 thr: 4 threads per h (f-slices of 256).
__global__ __launch_bounds__(256)
void query_kernel(const float* __restrict__ fuse, const float* __restrict__ wq,
                  float* __restrict__ query) {
    __shared__ float fsh[FUSEF];
    const int tid = threadIdx.x;
    const int b   = blockIdx.x >> 3;
    const int hcq = blockIdx.x & 7;
    fsh[tid]       = fuse[b * FUSEF + tid];
    fsh[tid + 256] = fuse[b * FUSEF + tid + 256];
    fsh[tid + 512] = fuse[b * FUSEF + tid + 512];
    fsh[tid + 768] = fuse[b * FUSEF + tid + 768];
    __syncthreads();
    const int hl = tid >> 2;          // 0..63
    const int fs = tid & 3;           // f-slice of 256
    const int h  = hcq * 64 + hl;
    const float* w  = wq + (long)h * FUSEF + fs * 256;
    const float* fl = fsh + fs * 256;
    float a0 = 0.f, a1 = 0.f, a2 = 0.f, a3 = 0.f;
    #pragma unroll 8
    for (int i = 0; i < 256; i += 4) {
        float4 wf = *(const float4*)(w + i);
        a0 += wf.x * fl[i];     a1 += wf.y * fl[i + 1];
        a2 += wf.z * fl[i + 2]; a3 += wf.w * fl[i + 3];
    }
    float s = (a0 + a1) + (a2 + a3);
    s += __shfl_xor(s, 1);
    s += __shfl_xor(s, 2);
    if (fs == 0) query[b * HIDH + h] = s;
}

// ---------------- K1b: pack Wk (f32 [512][512]) -> bf16, tiled+swizzled -----
// layout: [hc(2)][kk(8)] tiles of 32KB; within: byte = hl*128 + ((kloc*2) ^ ((hl&7)<<4))
__global__ __launch_bounds__(256)
void pack_wk(const float* __restrict__ wk, char* __restrict__ wkb) {
    const int u  = blockIdx.x * 256 + threadIdx.x;   // 0..32767 (16B units)
    const int h  = u >> 6;
    const int k0 = (u & 63) << 3;
    const float* src = wk + (long)h * CONC + k0;
    float4 f0 = *(const float4*)src;
    float4 f1 = *(const float4*)(src + 4);
    u16x8 v;
    v[0] = f2bf(f0.x); v[1] = f2bf(f0.y); v[2] = f2bf(f0.z); v[3] = f2bf(f0.w);
    v[4] = f2bf(f1.x); v[5] = f2bf(f1.y); v[6] = f2bf(f1.z); v[7] = f2bf(f1.w);
    const int hc = h >> 8, hl = h & 255, kk = k0 >> 6, kloc = k0 & 63;
    const int off = hc * 262144 + kk * 32768 + hl * 128 + (((kloc * 2)) ^ ((hl & 7) << 4));
    *(u16x8*)(wkb + off) = v;
}

// ---------------- K2: partial scores over a 256-H chunk ----------------------
// grid: (2 hc, 2048 rowgroups); 512 thr / 8 waves: wr=wid>>2 (32 rows), wc=wid&3 (64 h).
// LDS = 8K (A) + 32K (B) = 40960 -> target 3 blocks/CU (6 waves/EU).
__global__ __launch_bounds__(512, 6)
void score_kernel(const float* __restrict__ conf, const char* __restrict__ wkb,
                  const float* __restrict__ query, const float* __restrict__ wt,
                  float* __restrict__ sc_part) {
    __shared__ __align__(16) char As[64 * 128];    // 8 KB  bf16 swizzled
    __shared__ __align__(16) char Bs[256 * 128];   // 32 KB bf16 swizzled (pre-swz global)

    const int tid  = threadIdx.x;
    const int lane = tid & 63;
    const int wid  = tid >> 6;
    const int wr   = wid >> 2;
    const int wc   = wid & 3;
    const int hc   = blockIdx.x;                   // 0,1 (fastest -> L2 pairing)
    const long row0 = (long)blockIdx.y * 64;
    const int  b    = (int)(row0 >> 11);

    f32x4 acc[2][4] = {};

    const float* aGlob = conf + row0 * CONC;
    const int arow = tid >> 3;
    const int akc  = (tid & 7) << 3;
    const int aoff = arow * 128 + (((akc * 2)) ^ ((arow & 7) << 4));
    const char* bbase = wkb + hc * 262144;

    for (int kk = 0; kk < 8; ++kk) {
        // stage A: 64x64 f32 -> bf16 -> LDS (swizzled)
        {
            const float* src = aGlob + (long)arow * CONC + kk * 64 + akc;
            float4 f0 = *(const float4*)src;
            float4 f1 = *(const float4*)(src + 4);
            u16x8 v;
            v[0] = f2bf(f0.x); v[1] = f2bf(f0.y); v[2] = f2bf(f0.z); v[3] = f2bf(f0.w);
            v[4] = f2bf(f1.x); v[5] = f2bf(f1.y); v[6] = f2bf(f1.z); v[7] = f2bf(f1.w);
            *(u16x8*)(As + aoff) = v;
        }
        // stage B: 32KB pre-swizzled tile, linear global_load_lds
        {
            const char* btile = bbase + kk * 32768;
            #pragma unroll
            for (int i = 0; i < 4; ++i) {
                const int off = wid * 4096 + i * 1024;   // wave-uniform
                __builtin_amdgcn_global_load_lds(GLOBAL_U32(btile + off + (lane << 4)),
                                                 LDS_U32(Bs + off), 16, 0, 0);
            }
        }
        __syncthreads();
        #pragma unroll
        for (int ks = 0; ks < 2; ++ks) {
            const int kb = (ks * 32 + ((lane >> 4) << 3)) * 2;
            bf16x8 af[2];
            #pragma unroll
            for (int rf = 0; rf < 2; ++rf) {
                const int r = wr * 32 + rf * 16 + (lane & 15);
                af[rf] = *(const bf16x8*)(As + r * 128 + (kb ^ ((r & 7) << 4)));
            }
            bf16x8 bfr[4];
            #pragma unroll
            for (int cf = 0; cf < 4; ++cf) {
                const int hl2 = wc * 64 + cf * 16 + (lane & 15);
                bfr[cf] = *(const bf16x8*)(Bs + hl2 * 128 + (kb ^ ((hl2 & 7) << 4)));
            }
            #pragma unroll
            for (int rf = 0; rf < 2; ++rf)
                #pragma unroll
                for (int cf = 0; cf < 4; ++cf)
                    acc[rf][cf] = __builtin_amdgcn_mfma_f32_16x16x32_bf16(
                        af[rf], bfr[cf], acc[rf][cf], 0, 0, 0);
        }
        __syncthreads();
    }

    // epilogue: tanh(q+k)*wt, reduce over this block's 256 h
    float* spf = (float*)As;                       // alias (post-barrier)
    float qv[4], wv[4];
    #pragma unroll
    for (int cf = 0; cf < 4; ++cf) {
        const int c = wc * 64 + cf * 16 + (lane & 15);
        qv[cf] = query[b * HIDH + hc * 256 + c];
        wv[cf] = wt[hc * 256 + c];
    }
    float ps[2][4] = {};
    #pragma unroll
    for (int rf = 0; rf < 2; ++rf)
        #pragma unroll
        for (int cf = 0; cf < 4; ++cf)
            #pragma unroll
            for (int j = 0; j < 4; ++j)
                ps[rf][j] += fast_tanh(acc[rf][cf][j] + qv[cf]) * wv[cf];

    if (tid < 64) spf[tid] = 0.f;
    __syncthreads();
    #pragma unroll
    for (int m = 1; m < 16; m <<= 1)
        #pragma unroll
        for (int rf = 0; rf < 2; ++rf)
            #pragma unroll
            for (int j = 0; j < 4; ++j)
                ps[rf][j] += __shfl_xor(ps[rf][j], m);
    if ((lane & 15) == 0) {
        const int rb = wr * 32 + ((lane >> 4) << 2);
        #pragma unroll
        for (int rf = 0; rf < 2; ++rf)
            #pragma unroll
            for (int j = 0; j < 4; ++j)
                atomicAdd(&spf[rb + rf * 16 + j], ps[rf][j]);
    }
    __syncthreads();
    if (tid < 64) sc_part[(long)hc * (BB * NN) + row0 + tid] = spf[tid];
}

// ---------------- K3: softmax + weighted partial sums -----------------------
// grid: 64 b x 16 n-slices of 128; 256 thr. Wave reads 1KB contiguous.
__global__ __launch_bounds__(256)
void out_kernel(const float* __restrict__ conf, const float* __restrict__ prob,
                const float* __restrict__ sc0, const float* __restrict__ sc1,
                float* __restrict__ part) {
    __shared__ float wl[128];
    __shared__ float4 red4[128];
    __shared__ float smax[4], ssum[4];

    const int tid = threadIdx.x;
    const int b   = blockIdx.x >> 4;
    const int ns  = blockIdx.x & 15;
    const int n0  = ns * 128;
    const float* s0 = sc0 + b * NN;
    const float* s1 = sc1 + b * NN;

    // full-N softmax stats (redundant per block, trivial: 8 KB reads)
    float mx = -1e30f;
    for (int n = tid; n < NN; n += 256) mx = fmaxf(mx, s0[n] + s1[n]);
    #pragma unroll
    for (int m = 1; m < 64; m <<= 1) mx = fmaxf(mx, __shfl_xor(mx, m));
    if ((tid & 63) == 0) smax[tid >> 6] = mx;
    __syncthreads();
    mx = fmaxf(fmaxf(smax[0], smax[1]), fmaxf(smax[2], smax[3]));

    float sm = 0.f;
    for (int n = tid; n < NN; n += 256) sm += __expf(s0[n] + s1[n] - mx);
    #pragma unroll
    for (int m = 1; m < 64; m <<= 1) sm += __shfl_xor(sm, m);
    if ((tid & 63) == 0) ssum[tid >> 6] = sm;
    __syncthreads();
    const float rsum = 1.0f / (ssum[0] + ssum[1] + ssum[2] + ssum[3]);

    if (tid < 128) {
        const int n = n0 + tid;
        wl[tid] = __expf(s0[n] + s1[n] - mx) * prob[b * NN + n];
    }
    __syncthreads();

    // weighted sum over 128 rows x 512 cols
    const int tcol = tid & 127;             // col4 index
    const int trow = tid >> 7;              // 0,1
    const int col4 = tcol << 2;
    const float* cbase = conf + ((long)b * NN + n0) * CONC + col4;
    float4 acc = make_float4(0.f, 0.f, 0.f, 0.f);
    for (int r = trow; r < 128; r += 2) {
        const float w = wl[r];
        float4 v = *(const float4*)(cbase + (long)r * CONC);
        acc.x += w * v.x; acc.y += w * v.y; acc.z += w * v.z; acc.w += w * v.w;
    }
    if (trow == 1) red4[tcol] = acc;
    __syncthreads();
    if (trow == 0) {
        float4 t = red4[tcol];
        acc.x = (acc.x + t.x) * rsum; acc.y = (acc.y + t.y) * rsum;
        acc.z = (acc.z + t.z) * rsum; acc.w = (acc.w + t.w) * rsum;
        *(float4*)(part + ((long)ns * BB + b) * CONC + col4) = acc;
    }
}

// ---------------- K4: sum 16 partials -> fin ---------------------------------
__global__ __launch_bounds__(256)
void reduce_kernel(const float* __restrict__ part, float* __restrict__ fin) {
    const int idx = blockIdx.x * 256 + threadIdx.x;   // 0..32767 = b*512+c
    float s = 0.f;
    #pragma unroll
    for (int ns = 0; ns < 16; ++ns) s += part[ns * (BB * CONC) + idx];
    fin[idx] = s;
}

extern "C" void kernel_launch(void* const* d_in, const int* in_sizes, int n_in,
                              void* d_out, int out_size, void* d_ws, size_t ws_size,
                              hipStream_t stream) {
    const float* conf = (const float*)d_in[0];
    const float* fuse = (const float*)d_in[1];
    const float* prob = (const float*)d_in[2];
    const float* wq   = (const float*)d_in[3];
    const float* wk   = (const float*)d_in[4];
    const float* wt   = (const float*)d_in[5];
    float* out = (float*)d_out;
    char* ws = (char*)d_ws;

    float* q_ws  = (float*)ws;                        // 128 KB
    float* sc_ws = (float*)(ws + 131072);             // 2 x 64x2048 f32 = 1 MB
    char*  wkb   = ws + 131072 + 1048576;             // 512 KB swizzled tiles
    float* part  = (float*)(ws + 131072 + 1048576 + 524288);  // 16x64x512 f32 = 2 MB

    query_kernel<<<dim3(BB * 8), dim3(256), 0, stream>>>(fuse, wq, q_ws);
    pack_wk<<<dim3(128), dim3(256), 0, stream>>>(wk, wkb);
    score_kernel<<<dim3(2, 2048), dim3(512), 0, stream>>>(conf, wkb, q_ws, wt, sc_ws);
    out_kernel<<<dim3(BB * 16), dim3(256), 0, stream>>>(conf, prob, sc_ws, sc_ws + BB * NN, part);
    reduce_kernel<<<dim3(128), dim3(256), 0, stream>>>(part, out);
}